// Round 4
// baseline (176.108 us; speedup 1.0000x reference)
//
#include <hip/hip_runtime.h>
#include <stdint.h>

// Problem: out[m][n] = sum_k x[m][k] * w[n][k] + bias[n]
//   M=256, N=16384, K=4096, w = dequant(2-bit, group=16 along k)
// Round 4: finer barrier domains + bigger bodies.
//  - 256-thread blocks (4 waves, all m-split), BN=32, BM=128 -> grid (512,2)
//    = 1024 blocks = 4 blocks/CU = 4 independent barrier domains per CU.
//    A L2 traffic, dequant count, LDS traffic all UNCHANGED vs round 3
//    (old 2x wn-duplication of A exactly cancels the BN halving).
//  - BK=128 super-bodies (2 sub-tiles per barrier): 32 bodies instead of 64,
//    16 MFMA + 8 ds_read per wave per barrier; pointer-bump addressing.
//  - lgkm-only barrier, A ping-pong reg prefetch, q2 prefetch 2 bodies deep,
//    XOR-swizzled B LDS (unchanged scheme).
#define M_DIM 256
#define N_DIM 16384
#define K_DIM 4096
#define BN 32
#define BM 128
#define BK 128
#define NT2 (K_DIM / BK)   // 32 super-bodies

typedef __bf16 bf16x8 __attribute__((ext_vector_type(8)));
typedef float  f32x4  __attribute__((ext_vector_type(4)));

// fp32 -> bf16 bits, round-nearest-even (finite inputs)
__device__ __forceinline__ uint32_t f2bf(float f) {
  uint32_t u = __float_as_uint(f);
  return (u + 0x7fffu + ((u >> 16) & 1u)) >> 16;
}

// Barrier that waits ONLY on LDS ops (dbuf ordering) -- leaves global loads
// in flight across the barrier.
#define LDS_BARRIER() \
  asm volatile("s_waitcnt lgkmcnt(0)\n\ts_barrier" ::: "memory")

// ---------------------------------------------------------------------------
// Kernel 1 (unchanged): x fp32 [256][4096] -> bf16 fragment-chunk order.
// Chunk = (m-block of 16 rows) x (k-chunk of 32): 64 slots x 16B.
// Slot L holds row (L&15), k = (L>>4)*8 .. +7  (MFMA 16x16x32 A-frag order).
// ws uint4 index = (mb_glob*128 + kch)*64 + L.
// ---------------------------------------------------------------------------
__global__ __launch_bounds__(256) void cvt_x_kernel(const float* __restrict__ x,
                                                    uint4* __restrict__ ws) {
  int T = blockIdx.x * 256 + threadIdx.x;       // 0..131071
  int mb_glob = T >> 13;                        // 16 m-blocks
  int r       = T & 8191;
  int kch     = r >> 6;                         // 128 k-chunks
  int L       = r & 63;
  int row = mb_glob * 16 + (L & 15);
  int k   = kch * 32 + (L >> 4) * 8;
  const float* p = x + (size_t)row * K_DIM + k;
  float4 a = *(const float4*)p;
  float4 b = *(const float4*)(p + 4);
  uint4 o;
  o.x = f2bf(a.x) | (f2bf(a.y) << 16);
  o.y = f2bf(a.z) | (f2bf(a.w) << 16);
  o.z = f2bf(b.x) | (f2bf(b.y) << 16);
  o.w = f2bf(b.z) | (f2bf(b.w) << 16);
  ws[T] = o;
}

// ---------------------------------------------------------------------------
// Dequant 8 elems (2 packed q2 words; 4 crumbs in each low byte) of one group.
// Table entries {-n, a-n, 2a-n, 3a-n}, a = n*2/3 -- bit-identical to the
// fmaf+f2bf reference path.  v_perm_b32 picks the bf16 entry per crumb.
// ---------------------------------------------------------------------------
__device__ __forceinline__ uint4 deq8(uint2 q, float nv) {
  float a2 = nv * (2.0f / 3.0f);
  uint32_t tlo = f2bf(-nv) | (f2bf(fmaf(1.0f, a2, -nv)) << 16);
  uint32_t thi = f2bf(fmaf(2.0f, a2, -nv)) | (f2bf(fmaf(3.0f, a2, -nv)) << 16);
  uint32_t s0 = ((q.x & 3u) | ((q.x & 0xCu) << 14)) * 0x0202u + 0x01000100u;
  uint32_t s1 = (((q.x >> 4) & 3u) | ((q.x & 0xC0u) << 10)) * 0x0202u + 0x01000100u;
  uint32_t s2 = ((q.y & 3u) | ((q.y & 0xCu) << 14)) * 0x0202u + 0x01000100u;
  uint32_t s3 = (((q.y >> 4) & 3u) | ((q.y & 0xC0u) << 10)) * 0x0202u + 0x01000100u;
  uint4 r;
  r.x = __builtin_amdgcn_perm(thi, tlo, s0);
  r.y = __builtin_amdgcn_perm(thi, tlo, s1);
  r.z = __builtin_amdgcn_perm(thi, tlo, s2);
  r.w = __builtin_amdgcn_perm(thi, tlo, s3);
  return r;
}

// ---------------------------------------------------------------------------
// Kernel 2: grid (512,2), 256 threads, 4 waves (wm = wave id, 32 m-rows each;
// all waves share the 32 n-cols). Per super-body (BK=128 = 4 k-chunks):
// prefetch A(T+1) frags (8x uint4, ping-pong regs), 16 MFMA, dequant tile T+1
// (2 deq8/thread, q loaded 2 bodies earlier) into Bb[p^1], reload q(T+3),
// lgkm-only barrier.
// ---------------------------------------------------------------------------
__global__ __launch_bounds__(256, 4) void gemm2bit_kernel(
    const uint4*    __restrict__ aws,  // A chunks (see cvt)
    const uint32_t* __restrict__ q2,   // [G][4] packed 2-bit (low byte crumbs)
    const float*    __restrict__ nrm,  // [G] group norms (f32)
    const float*    __restrict__ bias, // [N]
    float*          __restrict__ out)  // [256][16384] fp32
{
  __shared__ uint4 Bb[2][512];  // 8 chunks (kch*2+nb) x 64 slots, dbuf = 16 KiB

  const int tid  = threadIdx.x;
  const int lane = tid & 63;
  const int w    = tid >> 6;    // 0..3 : rows m0 + w*32 .. +31
  const int lo4  = lane & 15;
  const int qd   = lane >> 4;
  const int n0   = blockIdx.x * BN;
  const int m0   = blockIdx.y * BM;

  // swizzled read lane: XOR qd into low 2 bits of lo4 (matches write swizzle)
  const int lrs = lane ^ qd;

  // --- B staging role: two half-groups (8 elems each) per thread ---
  const int nloc = tid >> 3;          // 0..31 n-row within tile
  const int kg   = (tid >> 1) & 3;    // k-group within 64-k half
  const int h    = tid & 1;           // half of the group
  const int grow = n0 + nloc;
  const int qd2  = (kg & 1) * 2 + h;
  const int swz  = (nloc & 15) ^ qd2;          // phys = logical ^ qd2
  // chunk c = (st*2 + (kg>>1))*2 + (nloc>>4), st = 0/1 (64-k half)
  const int bs0 = ((kg >> 1) * 2 + (nloc >> 4)) * 64 + qd2 * 16 + swz;
  const int bs1 = ((2 + (kg >> 1)) * 2 + (nloc >> 4)) * 64 + qd2 * 16 + swz;

  // --- pointers ---
  // A frag source: m-chunk mb = blockIdx.y*8 + w*2 + s, k-chunk kch: offset
  // (mb*128 + kch)*64 + lane  (uint4 units); s stride = 8192, kch stride = 64.
  const uint4* pA = aws + (size_t)(blockIdx.y * 8 + w * 2) * 8192 + lane;
  // q2: group gidx = grow*256 + T*8 + st*4 + kg; uint32 at gidx*4 + h*2
  const uint32_t* pq = q2 + ((size_t)grow * 256 + kg) * 4 + h * 2;
  const float*    pn = nrm + (size_t)grow * 256 + kg;

  f32x4 acc[2][2];
#pragma unroll
  for (int s = 0; s < 2; ++s)
#pragma unroll
    for (int u = 0; u < 2; ++u)
      acc[s][u] = (f32x4){0.f, 0.f, 0.f, 0.f};

  uint4 af0[8], af1[8];   // [s*4 + c]
  uint2 qa0, qa1, qb0, qb1;
  float na0, na1, nb0, nb1;

  // ---- prologue: tile0 A-frags + B dequant; q(1),q(2) prefetched ----
#pragma unroll
  for (int s = 0; s < 2; ++s)
#pragma unroll
    for (int c = 0; c < 4; ++c)
      af0[s * 4 + c] = pA[s * 8192 + c * 64];
  {
    uint2 x0 = *(const uint2*)pq;          // T=0, st=0
    uint2 x1 = *(const uint2*)(pq + 16);   // T=0, st=1
    float y0 = pn[0], y1 = pn[4];
    qa0 = *(const uint2*)(pq + 32);  qa1 = *(const uint2*)(pq + 48);   // q(1)
    na0 = pn[8];  na1 = pn[12];
    qb0 = *(const uint2*)(pq + 64);  qb1 = *(const uint2*)(pq + 80);   // q(2)
    nb0 = pn[16]; nb1 = pn[20];
    Bb[0][bs0] = deq8(x0, y0);
    Bb[0][bs1] = deq8(x1, y1);
  }
  LDS_BARRIER();
  const uint4* pAp = pA + 256;   // tile 1 A source (bumped +256/body)

  // Body T: MFMA tile T from Bb[PR]+AFC; prefetch A(T+1)->AFN; dequant tile
  // T+1 from Q* (loaded at body T-2) into Bb[PR^1]; reload Q*=q(T+3); barrier.
#define GEMM_BODY(T, PR, AFC, AFN, Q0, Q1, N0v, N1v)                            \
  do {                                                                          \
    if ((T) + 1 < NT2) {                                                        \
      _Pragma("unroll")                                                         \
      for (int s = 0; s < 2; ++s)                                               \
        _Pragma("unroll")                                                       \
        for (int c = 0; c < 4; ++c)                                             \
          AFN[s * 4 + c] = pAp[s * 8192 + c * 64];                              \
    }                                                                           \
    _Pragma("unroll")                                                           \
    for (int c = 0; c < 4; ++c) {                                               \
      bf16x8 bfv[2];                                                            \
      _Pragma("unroll")                                                         \
      for (int u = 0; u < 2; ++u)                                               \
        bfv[u] = *(const bf16x8*)&Bb[PR][(c * 2 + u) * 64 + lrs];               \
      _Pragma("unroll")                                                         \
      for (int s = 0; s < 2; ++s) {                                             \
        bf16x8 av = __builtin_bit_cast(bf16x8, AFC[s * 4 + c]);                 \
        _Pragma("unroll")                                                       \
        for (int u = 0; u < 2; ++u)                                             \
          acc[s][u] = __builtin_amdgcn_mfma_f32_16x16x32_bf16(av, bfv[u],       \
                                                              acc[s][u], 0, 0, 0);\
      }                                                                         \
    }                                                                           \
    if ((T) + 1 < NT2) {                                                        \
      Bb[(PR) ^ 1][bs0] = deq8(Q0, N0v);                                        \
      Bb[(PR) ^ 1][bs1] = deq8(Q1, N1v);                                        \
    }                                                                           \
    if ((T) + 3 < NT2) {                                                        \
      Q0  = *(const uint2*)(pq + (size_t)((T) + 3) * 32);                       \
      Q1  = *(const uint2*)(pq + (size_t)((T) + 3) * 32 + 16);                  \
      N0v = pn[(size_t)((T) + 3) * 8];                                          \
      N1v = pn[(size_t)((T) + 3) * 8 + 4];                                      \
    }                                                                           \
    pAp += 256;                                                                 \
    LDS_BARRIER();                                                              \
  } while (0)

  for (int t2 = 0; t2 < NT2; t2 += 2) {
    GEMM_BODY(t2,     0, af0, af1, qa0, qa1, na0, na1);
    GEMM_BODY(t2 + 1, 1, af1, af0, qb0, qb1, nb0, nb1);
  }
#undef GEMM_BODY

  // ---- epilogue: direct store, C/D layout col=lane&15 (n),
  // row=(lane>>4)*4+reg (m) ----
  float bv[2];
#pragma unroll
  for (int u = 0; u < 2; ++u)
    bv[u] = bias[n0 + u * 16 + lo4];

#pragma unroll
  for (int s = 0; s < 2; ++s) {
    int mrow = m0 + w * 32 + s * 16 + qd * 4;
#pragma unroll
    for (int u = 0; u < 2; ++u) {
      int ncol = n0 + u * 16 + lo4;
      float* p = out + (size_t)mrow * N_DIM + ncol;
#pragma unroll
      for (int r = 0; r < 4; ++r)
        p[(size_t)r * N_DIM] = acc[s][u][r] + bv[u];
    }
  }
}

// ---------------------------------------------------------------------------
extern "C" void kernel_launch(void* const* d_in, const int* in_sizes, int n_in,
                              void* d_out, int out_size, void* d_ws, size_t ws_size,
                              hipStream_t stream) {
  const float*    x    = (const float*)d_in[0];
  const uint32_t* q2   = (const uint32_t*)d_in[1];
  const float*    nm   = (const float*)d_in[2];
  const float*    bias = (const float*)d_in[3];
  float*          out  = (float*)d_out;
  uint4*          aws  = (uint4*)d_ws;   // 2 MiB: x as bf16 fragment chunks

  cvt_x_kernel<<<512, 256, 0, stream>>>(x, aws);
  gemm2bit_kernel<<<dim3(N_DIM / BN, 2), 256, 0, stream>>>(aws, q2, nm, bias, out);
}